// Round 5
// baseline (241.653 us; speedup 1.0000x reference)
//
#include <hip/hip_runtime.h>

// Fused grouped 4-layer MLP: 64 models × 32768 tokens, d=64, fp32 in/out,
// f16 MFMA (fp32 accumulate) inside.
//
// R5 = R4 + prefetch depth 2: tile loop unrolled x2 with two named register
// buffers (A,B), no swap movs. Each iteration: cvt(cur) -> issue loads for
// tile+2 into cur's regs -> 32 MFMA -> store. Every wave holds 2x4KB loads
// in flight continuously (R4 held 1x4KB and the xr=xn swap let the compiler
// hoist the vmcnt wait). R4: 233 us = 4.9 TB/s vs fills' 6.6 TB/s.
//
// W fragments (32 KB) + bias (1 KB, exact f32) live in LDS, shared by the
// block's 4 waves (same model). Orientation: D[f][tok] (A = W rows=features,
// B = Z^T cols=tokens). k-map for BOTH operands:
// k = 32*kk + 16*(j>>2) + 4*g + (j&3) (bijection -> MFMA result independent
// of HW intra-lane k order). C/D layout: col=lane&15 = token,
// row = 4*(lane>>4)+reg = feature -> next layer's B fragment is a pure
// in-lane relu+cast repack of the accumulator. No inter-wave comms.

typedef __attribute__((ext_vector_type(8))) _Float16 f16x8;
typedef __attribute__((ext_vector_type(2))) __fp16 fp16x2; // cvt_pkrtz's native type
typedef __attribute__((ext_vector_type(4))) float f32x4;

#define MODELS 64
#define LAYERS 4
#define DIM 64
#define TOKS_PER_MODEL 32768
#define BLOCKS_PER_MODEL 16
#define WAVES_PER_BLOCK 4
#define TOK_PER_WAVE (TOKS_PER_MODEL / (BLOCKS_PER_MODEL * WAVES_PER_BLOCK)) // 512
#define TILES_PER_WAVE (TOK_PER_WAVE / 16) // 32

#define WF_BYTES (LAYERS * 4 * 2 * 64 * 16)       // 32768: [l][t][kk][lane] f16x8
#define BIAS_OFF WF_BYTES                          // [l][64] f32
#define LDS_BYTES (WF_BYTES + LAYERS * DIM * 4)    // 33792

union H8 { f16x8 v; fp16x2 h2[4]; };

// Issue 4 coalesced 16B loads for tile T into D0..D3 (1 KB/instr per wave).
#define LOAD4(D0, D1, D2, D3, T)                                   \
    {                                                              \
        const float* nx_ = xp + (size_t)(T) * (16 * DIM);          \
        D0 = *(const f32x4*)(nx_ + 0);                             \
        D1 = *(const f32x4*)(nx_ + 16);                            \
        D2 = *(const f32x4*)(nx_ + 32);                            \
        D3 = *(const f32x4*)(nx_ + 48);                            \
    }

// cvt cur tile to f16 B-fragments z0/z1 (packed RTZ).
#define CVT_Z(X0, X1, X2, X3)                                      \
    {                                                              \
        H8 z0u_, z1u_;                                             \
        z0u_.h2[0] = __builtin_amdgcn_cvt_pkrtz(X0[0], X0[1]);     \
        z0u_.h2[1] = __builtin_amdgcn_cvt_pkrtz(X0[2], X0[3]);     \
        z0u_.h2[2] = __builtin_amdgcn_cvt_pkrtz(X1[0], X1[1]);     \
        z0u_.h2[3] = __builtin_amdgcn_cvt_pkrtz(X1[2], X1[3]);     \
        z1u_.h2[0] = __builtin_amdgcn_cvt_pkrtz(X2[0], X2[1]);     \
        z1u_.h2[1] = __builtin_amdgcn_cvt_pkrtz(X2[2], X2[3]);     \
        z1u_.h2[2] = __builtin_amdgcn_cvt_pkrtz(X3[0], X3[1]);     \
        z1u_.h2[3] = __builtin_amdgcn_cvt_pkrtz(X3[2], X3[3]);     \
        z0 = z0u_.v; z1 = z1u_.v;                                  \
    }

// 4-layer MFMA chain on z0/z1, then store tile T (relu'd f32).
#define COMPUTE_STORE(T)                                                         \
    {                                                                            \
        f32x4 acc[4];                                                            \
        _Pragma("unroll")                                                        \
        for (int l = 0; l < LAYERS; ++l) {                                       \
            _Pragma("unroll")                                                    \
            for (int t = 0; t < 4; ++t)                                          \
                acc[t] = *(const f32x4*)(smem + BIAS_OFF + l * 256 + t * 64 + g * 16); \
            _Pragma("unroll")                                                    \
            for (int t = 0; t < 4; ++t) {                                        \
                f16x8 w0 = *(const f16x8*)(smem + ((size_t)((l * 4 + t) * 2 + 0) * 1024) + lane * 16); \
                acc[t] = __builtin_amdgcn_mfma_f32_16x16x32_f16(w0, z0, acc[t], 0, 0, 0); \
            }                                                                    \
            _Pragma("unroll")                                                    \
            for (int t = 0; t < 4; ++t) {                                        \
                f16x8 w1 = *(const f16x8*)(smem + ((size_t)((l * 4 + t) * 2 + 1) * 1024) + lane * 16); \
                acc[t] = __builtin_amdgcn_mfma_f32_16x16x32_f16(w1, z1, acc[t], 0, 0, 0); \
            }                                                                    \
            if (l < LAYERS - 1) {                                                \
                H8 n0, n1;                                                       \
                _Pragma("unroll")                                                \
                for (int t = 0; t < 2; ++t) {                                    \
                    n0.h2[t * 2 + 0] = __builtin_amdgcn_cvt_pkrtz(               \
                        fmaxf(acc[t][0], 0.0f), fmaxf(acc[t][1], 0.0f));         \
                    n0.h2[t * 2 + 1] = __builtin_amdgcn_cvt_pkrtz(               \
                        fmaxf(acc[t][2], 0.0f), fmaxf(acc[t][3], 0.0f));         \
                    n1.h2[t * 2 + 0] = __builtin_amdgcn_cvt_pkrtz(               \
                        fmaxf(acc[2 + t][0], 0.0f), fmaxf(acc[2 + t][1], 0.0f)); \
                    n1.h2[t * 2 + 1] = __builtin_amdgcn_cvt_pkrtz(               \
                        fmaxf(acc[2 + t][2], 0.0f), fmaxf(acc[2 + t][3], 0.0f)); \
                }                                                                \
                z0 = n0.v; z1 = n1.v;                                            \
            }                                                                    \
        }                                                                        \
        float* o_ = op + (size_t)(T) * (16 * DIM);                               \
        _Pragma("unroll")                                                        \
        for (int t = 0; t < 4; ++t) {                                            \
            f32x4 res;                                                           \
            _Pragma("unroll")                                                    \
            for (int r = 0; r < 4; ++r) res[r] = fmaxf(acc[t][r], 0.0f);         \
            *(f32x4*)(o_ + t * 16) = res;                                        \
        }                                                                        \
    }

__global__ __launch_bounds__(256, 2) void mlp4_fused(
    const float* __restrict__ x, const float* __restrict__ W,
    const float* __restrict__ b, float* __restrict__ out) {

    __shared__ __align__(16) unsigned char smem[LDS_BYTES];

    const int lane = threadIdx.x & 63;
    const int wave = threadIdx.x >> 6;
    const int c = lane & 15;   // token column (B/D) and W feature row (A)
    const int g = lane >> 4;   // k-group

    const int m   = blockIdx.x / BLOCKS_PER_MODEL;
    const int blk = blockIdx.x % BLOCKS_PER_MODEL;
    const size_t tok0 = (size_t)m * TOKS_PER_MODEL
                      + (size_t)(blk * WAVES_PER_BLOCK + wave) * TOK_PER_WAVE;

    // ---- stage this wave's layer (l = wave) of W into LDS ----
    // wf[l][t][kk] element j = f16(W[m][l][16t + c][32kk + 16*(j>>2) + 4g + (j&3)])
    {
        const int l = wave;
        const float* Wl = W + ((size_t)m * LAYERS + l) * DIM * DIM;
        #pragma unroll
        for (int t = 0; t < 4; ++t) {
            const float* row = Wl + (size_t)(t * 16 + c) * DIM + 4 * g;
            f32x4 c0 = *(const f32x4*)(row + 0);
            f32x4 c1 = *(const f32x4*)(row + 16);
            f32x4 c2 = *(const f32x4*)(row + 32);
            f32x4 c3 = *(const f32x4*)(row + 48);
            H8 a0, a1;
            #pragma unroll
            for (int e = 0; e < 4; ++e) {
                a0.v[e]     = (_Float16)c0[e];  // RNE for weights (one-time)
                a0.v[4 + e] = (_Float16)c1[e];
                a1.v[e]     = (_Float16)c2[e];
                a1.v[4 + e] = (_Float16)c3[e];
            }
            *(f16x8*)(smem + ((size_t)((l * 4 + t) * 2 + 0) * 1024) + lane * 16) = a0.v;
            *(f16x8*)(smem + ((size_t)((l * 4 + t) * 2 + 1) * 1024) + lane * 16) = a1.v;
        }
        // bias layer l, exact f32: 64 floats
        if (lane < 16) {
            const float* bl = b + ((size_t)m * LAYERS + l) * DIM + lane * 4;
            *(f32x4*)(smem + BIAS_OFF + l * 256 + lane * 16) = *(const f32x4*)bl;
        }
    }
    __syncthreads();

    // Lane's global base: token (tok0 + c), column offset 4g.
    const float* xp = x   + tok0 * DIM + (size_t)(c * DIM + 4 * g);
    float*       op = out + tok0 * DIM + (size_t)(c * DIM + 4 * g);

    // Prologue: buffers A = tile 0, B = tile 1 (depth-2 pipeline).
    f32x4 A0, A1, A2, A3, B0, B1, B2, B3;
    LOAD4(A0, A1, A2, A3, 0);
    LOAD4(B0, B1, B2, B3, 1);

    f16x8 z0, z1;

    #pragma unroll 1
    for (int tp = 0; tp < TILES_PER_WAVE / 2; ++tp) {
        const int t0 = 2 * tp;
        const int t1 = 2 * tp + 1;

        // even phase: consume A (tile t0), refill A with tile t0+2
        CVT_Z(A0, A1, A2, A3);
        LOAD4(A0, A1, A2, A3, (t0 + 2) & (TILES_PER_WAVE - 1));
        COMPUTE_STORE(t0);

        // odd phase: consume B (tile t1), refill B with tile t1+2
        CVT_Z(B0, B1, B2, B3);
        LOAD4(B0, B1, B2, B3, (t1 + 2) & (TILES_PER_WAVE - 1));
        COMPUTE_STORE(t1);
    }
}

extern "C" void kernel_launch(void* const* d_in, const int* in_sizes, int n_in,
                              void* d_out, int out_size, void* d_ws, size_t ws_size,
                              hipStream_t stream) {
    (void)in_sizes; (void)n_in; (void)out_size; (void)d_ws; (void)ws_size;
    const float* x = (const float*)d_in[0];
    const float* W = (const float*)d_in[1];
    const float* b = (const float*)d_in[2];
    float* out = (float*)d_out;
    mlp4_fused<<<dim3(MODELS * BLOCKS_PER_MODEL), dim3(256), 0, stream>>>(x, W, b, out);
}

// Round 6
// 241.268 us; speedup vs baseline: 1.0016x; 1.0016x over previous
//
#include <hip/hip_runtime.h>

// Fused grouped 4-layer MLP: 64 models × 32768 tokens, d=64, fp32 in/out,
// f16 MFMA (fp32 accumulate) inside.
//
// R6 vs R4/R5: 32-token tiles = two 16-token halves (A,B) computed inside the
// same layer loop, SHARING each W ds_read (halves W LDS traffic: 16->8 MB/CU)
// and cutting per-token VALU/DS instruction counts ~25-40%. x registers are
// reused: cvt cur tile -> z (f16), then next-tile loads target the SAME X
// regs (no double buffer, no swap movs). Est. ~110 VGPR -> <=128 tier ->
// 4 blocks/CU, grid 1024 = 256x4 exact (no tail round).
// R5 lesson: prefetch depth 2 did NOT help (233->242) -> not latency-bound;
// gap vs 6.3 TB/s is LDS/VALU issue overhead + occupancy tier.
//
// W fragments (32 KB) + bias (1 KB, exact f32) live in LDS, shared by the
// block's 4 waves (same model). Orientation: D[f][tok] (A = W rows=features,
// B = Z^T cols=tokens). k-map for BOTH operands:
// k = 32*kk + 16*(j>>2) + 4*g + (j&3) (bijection -> MFMA result independent
// of HW intra-lane k order). C/D layout: col=lane&15 = token,
// row = 4*(lane>>4)+reg = feature -> next layer's B fragment is a pure
// in-lane relu+cast repack of the accumulator. No inter-wave comms.

typedef __attribute__((ext_vector_type(8))) _Float16 f16x8;
typedef __attribute__((ext_vector_type(2))) __fp16 fp16x2; // cvt_pkrtz's native type
typedef __attribute__((ext_vector_type(4))) float f32x4;

#define MODELS 64
#define LAYERS 4
#define DIM 64
#define TOKS_PER_MODEL 32768
#define BLOCKS_PER_MODEL 16
#define WAVES_PER_BLOCK 4
#define TOK_PER_WAVE (TOKS_PER_MODEL / (BLOCKS_PER_MODEL * WAVES_PER_BLOCK)) // 512
#define TILE_TOKS 32
#define TILES_PER_WAVE (TOK_PER_WAVE / TILE_TOKS) // 16

#define WF_BYTES (LAYERS * 4 * 2 * 64 * 16)       // 32768: [l][t][kk][lane] f16x8
#define BIAS_OFF WF_BYTES                          // [l][64] f32
#define LDS_BYTES (WF_BYTES + LAYERS * DIM * 4)    // 33792

union H8 { f16x8 v; fp16x2 h2[4]; };

// 4 coalesced 16B loads for a 16-token half starting at float* P.
#define LOAD4(D0, D1, D2, D3, P)                                   \
    {                                                              \
        D0 = *(const f32x4*)((P) + 0);                             \
        D1 = *(const f32x4*)((P) + 16);                            \
        D2 = *(const f32x4*)((P) + 32);                            \
        D3 = *(const f32x4*)((P) + 48);                            \
    }

// cvt one 16-token half to f16 B-fragments Z0/Z1 (packed RTZ).
#define CVT_Z(Z0, Z1, X0, X1, X2, X3)                              \
    {                                                              \
        H8 z0u_, z1u_;                                             \
        z0u_.h2[0] = __builtin_amdgcn_cvt_pkrtz(X0[0], X0[1]);     \
        z0u_.h2[1] = __builtin_amdgcn_cvt_pkrtz(X0[2], X0[3]);     \
        z0u_.h2[2] = __builtin_amdgcn_cvt_pkrtz(X1[0], X1[1]);     \
        z0u_.h2[3] = __builtin_amdgcn_cvt_pkrtz(X1[2], X1[3]);     \
        z1u_.h2[0] = __builtin_amdgcn_cvt_pkrtz(X2[0], X2[1]);     \
        z1u_.h2[1] = __builtin_amdgcn_cvt_pkrtz(X2[2], X2[3]);     \
        z1u_.h2[2] = __builtin_amdgcn_cvt_pkrtz(X3[0], X3[1]);     \
        z1u_.h2[3] = __builtin_amdgcn_cvt_pkrtz(X3[2], X3[3]);     \
        Z0 = z0u_.v; Z1 = z1u_.v;                                  \
    }

// relu+cvt repack of acc -> next layer's B fragments for one half.
#define REPACK(Z0, Z1, ACC)                                                  \
    {                                                                        \
        H8 n0_, n1_;                                                         \
        _Pragma("unroll")                                                    \
        for (int t_ = 0; t_ < 2; ++t_) {                                     \
            n0_.h2[t_ * 2 + 0] = __builtin_amdgcn_cvt_pkrtz(                 \
                fmaxf(ACC[t_][0], 0.0f), fmaxf(ACC[t_][1], 0.0f));           \
            n0_.h2[t_ * 2 + 1] = __builtin_amdgcn_cvt_pkrtz(                 \
                fmaxf(ACC[t_][2], 0.0f), fmaxf(ACC[t_][3], 0.0f));           \
            n1_.h2[t_ * 2 + 0] = __builtin_amdgcn_cvt_pkrtz(                 \
                fmaxf(ACC[2 + t_][0], 0.0f), fmaxf(ACC[2 + t_][1], 0.0f));   \
            n1_.h2[t_ * 2 + 1] = __builtin_amdgcn_cvt_pkrtz(                 \
                fmaxf(ACC[2 + t_][2], 0.0f), fmaxf(ACC[2 + t_][3], 0.0f));   \
        }                                                                    \
        Z0 = n0_.v; Z1 = n1_.v;                                              \
    }

__global__ __launch_bounds__(256, 2) void mlp4_fused(
    const float* __restrict__ x, const float* __restrict__ W,
    const float* __restrict__ b, float* __restrict__ out) {

    __shared__ __align__(16) unsigned char smem[LDS_BYTES];

    const int lane = threadIdx.x & 63;
    const int wave = threadIdx.x >> 6;
    const int c = lane & 15;   // token column (B/D) and W feature row (A)
    const int g = lane >> 4;   // k-group

    const int m   = blockIdx.x / BLOCKS_PER_MODEL;
    const int blk = blockIdx.x % BLOCKS_PER_MODEL;
    const size_t tok0 = (size_t)m * TOKS_PER_MODEL
                      + (size_t)(blk * WAVES_PER_BLOCK + wave) * TOK_PER_WAVE;

    // ---- stage this wave's layer (l = wave) of W into LDS ----
    // wf[l][t][kk] element j = f16(W[m][l][16t + c][32kk + 16*(j>>2) + 4g + (j&3)])
    {
        const int l = wave;
        const float* Wl = W + ((size_t)m * LAYERS + l) * DIM * DIM;
        #pragma unroll
        for (int t = 0; t < 4; ++t) {
            const float* row = Wl + (size_t)(t * 16 + c) * DIM + 4 * g;
            f32x4 c0 = *(const f32x4*)(row + 0);
            f32x4 c1 = *(const f32x4*)(row + 16);
            f32x4 c2 = *(const f32x4*)(row + 32);
            f32x4 c3 = *(const f32x4*)(row + 48);
            H8 a0, a1;
            #pragma unroll
            for (int e = 0; e < 4; ++e) {
                a0.v[e]     = (_Float16)c0[e];  // RNE for weights (one-time)
                a0.v[4 + e] = (_Float16)c1[e];
                a1.v[e]     = (_Float16)c2[e];
                a1.v[4 + e] = (_Float16)c3[e];
            }
            *(f16x8*)(smem + ((size_t)((l * 4 + t) * 2 + 0) * 1024) + lane * 16) = a0.v;
            *(f16x8*)(smem + ((size_t)((l * 4 + t) * 2 + 1) * 1024) + lane * 16) = a1.v;
        }
        // bias layer l, exact f32: 64 floats
        if (lane < 16) {
            const float* bl = b + ((size_t)m * LAYERS + l) * DIM + lane * 4;
            *(f32x4*)(smem + BIAS_OFF + l * 256 + lane * 16) = *(const f32x4*)bl;
        }
    }
    __syncthreads();

    // Lane's global base: token (tok0 + c), column offset 4g.
    const float* xp = x   + tok0 * DIM + (size_t)(c * DIM + 4 * g);
    float*       op = out + tok0 * DIM + (size_t)(c * DIM + 4 * g);

    // X regs: current tile's raw f32 (two halves); refilled after cvt.
    f32x4 XA0, XA1, XA2, XA3, XB0, XB1, XB2, XB3;
    LOAD4(XA0, XA1, XA2, XA3, xp + 0 * (16 * DIM));
    LOAD4(XB0, XB1, XB2, XB3, xp + 1 * (16 * DIM)); // half B = tokens +16

    #pragma unroll 1
    for (int tile = 0; tile < TILES_PER_WAVE; ++tile) {
        // cvt current tile (both halves) to f16 fragments, freeing X regs
        f16x8 zA0, zA1, zB0, zB1;
        CVT_Z(zA0, zA1, XA0, XA1, XA2, XA3);
        CVT_Z(zB0, zB1, XB0, XB1, XB2, XB3);

        // issue next tile's 8 loads into the SAME X regs (WAR: after cvt)
        const int nxt = (tile + 1) & (TILES_PER_WAVE - 1);
        const float* nx = xp + (size_t)nxt * (TILE_TOKS * DIM);
        LOAD4(XA0, XA1, XA2, XA3, nx + 0 * (16 * DIM));
        LOAD4(XB0, XB1, XB2, XB3, nx + 1 * (16 * DIM));

        // 4-layer chain, halves A and B sharing every W ds_read
        f32x4 accA[4], accB[4];
        #pragma unroll
        for (int l = 0; l < LAYERS; ++l) {
            #pragma unroll
            for (int t = 0; t < 4; ++t) {
                f32x4 bv = *(const f32x4*)(smem + BIAS_OFF + l * 256 + t * 64 + g * 16);
                accA[t] = bv;
                accB[t] = bv;
            }
            #pragma unroll
            for (int t = 0; t < 4; ++t) {
                f16x8 w0 = *(const f16x8*)(smem + ((size_t)((l * 4 + t) * 2 + 0) * 1024) + lane * 16);
                accA[t] = __builtin_amdgcn_mfma_f32_16x16x32_f16(w0, zA0, accA[t], 0, 0, 0);
                accB[t] = __builtin_amdgcn_mfma_f32_16x16x32_f16(w0, zB0, accB[t], 0, 0, 0);
            }
            #pragma unroll
            for (int t = 0; t < 4; ++t) {
                f16x8 w1 = *(const f16x8*)(smem + ((size_t)((l * 4 + t) * 2 + 1) * 1024) + lane * 16);
                accA[t] = __builtin_amdgcn_mfma_f32_16x16x32_f16(w1, zA1, accA[t], 0, 0, 0);
                accB[t] = __builtin_amdgcn_mfma_f32_16x16x32_f16(w1, zB1, accB[t], 0, 0, 0);
            }
            if (l < LAYERS - 1) {
                REPACK(zA0, zA1, accA);
                REPACK(zB0, zB1, accB);
            }
        }

        // stores: f = 16t + 4g + r -> r contiguous -> dwordx4
        float* oA = op + (size_t)tile * (TILE_TOKS * DIM);
        float* oB = oA + 16 * DIM;
        #pragma unroll
        for (int t = 0; t < 4; ++t) {
            f32x4 rA, rB;
            #pragma unroll
            for (int r = 0; r < 4; ++r) {
                rA[r] = fmaxf(accA[t][r], 0.0f);
                rB[r] = fmaxf(accB[t][r], 0.0f);
            }
            *(f32x4*)(oA + t * 16) = rA;
            *(f32x4*)(oB + t * 16) = rB;
        }
    }
}

extern "C" void kernel_launch(void* const* d_in, const int* in_sizes, int n_in,
                              void* d_out, int out_size, void* d_ws, size_t ws_size,
                              hipStream_t stream) {
    (void)in_sizes; (void)n_in; (void)out_size; (void)d_ws; (void)ws_size;
    const float* x = (const float*)d_in[0];
    const float* W = (const float*)d_in[1];
    const float* b = (const float*)d_in[2];
    float* out = (float*)d_out;
    mlp4_fused<<<dim3(MODELS * BLOCKS_PER_MODEL), dim3(256), 0, stream>>>(x, W, b, out);
}

// Round 7
// 228.393 us; speedup vs baseline: 1.0581x; 1.0564x over previous
//
#include <hip/hip_runtime.h>

// Fused grouped 4-layer MLP: 64 models × 32768 tokens, d=64, fp32 in/out,
// f16 MFMA (fp32 accumulate) inside.
//
// R7 = R4 with ONE change: tile->token interleave. R4/R5/R6 all plateau at
// 233-242 us (4.9 TB/s) while pure copies hit 6.3-6.6: the invariant across
// those rounds is the access ORDER. Wave-contiguous partitions give 4096
// scattered read pointers + 4096 write pointers over 1 GB -> ~16R+16W
// unrelated streams per HBM pseudo-channel -> DRAM row thrash. Fix: model
// m's 64 waves (16 blocks x 4) process tile s*64+q at step s, so each model
// sweeps ONE contiguous 256-KB window per step (64 compact windows device-
// wide instead of 8192 pointers). Compute structure identical to R4.
//
// W fragments (32 KB) + bias (1 KB, exact f32) live in LDS, shared by the
// block's 4 waves (same model). Orientation: D[f][tok] (A = W rows=features,
// B = Z^T cols=tokens). k-map for BOTH operands:
// k = 32*kk + 16*(j>>2) + 4*g + (j&3) (bijection -> MFMA result independent
// of HW intra-lane k order). C/D layout: col=lane&15 = token,
// row = 4*(lane>>4)+reg = feature -> next layer's B fragment is a pure
// in-lane relu+cast repack of the accumulator. No inter-wave comms.

typedef __attribute__((ext_vector_type(8))) _Float16 f16x8;
typedef __attribute__((ext_vector_type(2))) __fp16 fp16x2; // cvt_pkrtz's native type
typedef __attribute__((ext_vector_type(4))) float f32x4;

#define MODELS 64
#define LAYERS 4
#define DIM 64
#define TOKS_PER_MODEL 32768
#define BLOCKS_PER_MODEL 16
#define WAVES_PER_BLOCK 4
#define WAVES_PER_MODEL (BLOCKS_PER_MODEL * WAVES_PER_BLOCK)    // 64
#define STEPS 32                                                 // tiles per wave
#define STEP_FLOATS ((size_t)WAVES_PER_MODEL * 16 * DIM)         // 65536 (256 KB)

#define WF_BYTES (LAYERS * 4 * 2 * 64 * 16)       // 32768: [l][t][kk][lane] f16x8
#define BIAS_OFF WF_BYTES                          // [l][64] f32
#define LDS_BYTES (WF_BYTES + LAYERS * DIM * 4)    // 33792

union H8 { f16x8 v; fp16x2 h2[4]; };

__global__ __launch_bounds__(256, 2) void mlp4_fused(
    const float* __restrict__ x, const float* __restrict__ W,
    const float* __restrict__ b, float* __restrict__ out) {

    __shared__ __align__(16) unsigned char smem[LDS_BYTES];

    const int lane = threadIdx.x & 63;
    const int wave = threadIdx.x >> 6;
    const int c = lane & 15;   // token column (B/D) and W feature row (A)
    const int g = lane >> 4;   // k-group

    const int m   = blockIdx.x / BLOCKS_PER_MODEL;
    const int blk = blockIdx.x % BLOCKS_PER_MODEL;
    const int q   = blk * WAVES_PER_BLOCK + wave;   // wave index within model, 0..63

    // ---- stage this wave's layer (l = wave) of W into LDS ----
    // wf[l][t][kk] element j = f16(W[m][l][16t + c][32kk + 16*(j>>2) + 4g + (j&3)])
    {
        const int l = wave;
        const float* Wl = W + ((size_t)m * LAYERS + l) * DIM * DIM;
        #pragma unroll
        for (int t = 0; t < 4; ++t) {
            const float* row = Wl + (size_t)(t * 16 + c) * DIM + 4 * g;
            f32x4 c0 = *(const f32x4*)(row + 0);
            f32x4 c1 = *(const f32x4*)(row + 16);
            f32x4 c2 = *(const f32x4*)(row + 32);
            f32x4 c3 = *(const f32x4*)(row + 48);
            H8 a0, a1;
            #pragma unroll
            for (int e = 0; e < 4; ++e) {
                a0.v[e]     = (_Float16)c0[e];  // RNE for weights (one-time)
                a0.v[4 + e] = (_Float16)c1[e];
                a1.v[e]     = (_Float16)c2[e];
                a1.v[4 + e] = (_Float16)c3[e];
            }
            *(f16x8*)(smem + ((size_t)((l * 4 + t) * 2 + 0) * 1024) + lane * 16) = a0.v;
            *(f16x8*)(smem + ((size_t)((l * 4 + t) * 2 + 1) * 1024) + lane * 16) = a1.v;
        }
        // bias layer l, exact f32: 64 floats
        if (lane < 16) {
            const float* bl = b + ((size_t)m * LAYERS + l) * DIM + lane * 4;
            *(f32x4*)(smem + BIAS_OFF + l * 256 + lane * 16) = *(const f32x4*)bl;
        }
    }
    __syncthreads();

    // Lane's base: model m, wave-slot q's 16 tokens, token (q*16 + c), col 4g.
    // Step s advances by 1024 tokens (the model's 64 waves side by side).
    const float* xp = x   + ((size_t)m * TOKS_PER_MODEL + (size_t)q * 16) * DIM
                          + (size_t)(c * DIM + 4 * g);
    float*       op = out + ((size_t)m * TOKS_PER_MODEL + (size_t)q * 16) * DIM
                          + (size_t)(c * DIM + 4 * g);

    f32x4 xr0 = *(const f32x4*)(xp + 0);
    f32x4 xr1 = *(const f32x4*)(xp + 16);
    f32x4 xr2 = *(const f32x4*)(xp + 32);
    f32x4 xr3 = *(const f32x4*)(xp + 48);

    #pragma unroll 1
    for (int s = 0; s < STEPS; ++s) {
        // register-double-buffered prefetch of next step's x (+256 KB stride)
        const int nxt = (s + 1) & (STEPS - 1);
        const float* nx = xp + (size_t)nxt * STEP_FLOATS;
        f32x4 xn0 = *(const f32x4*)(nx + 0);
        f32x4 xn1 = *(const f32x4*)(nx + 16);
        f32x4 xn2 = *(const f32x4*)(nx + 32);
        f32x4 xn3 = *(const f32x4*)(nx + 48);

        // layer-0 B fragments from current x registers (packed cvt, RTZ)
        H8 z0u, z1u;
        z0u.h2[0] = __builtin_amdgcn_cvt_pkrtz(xr0[0], xr0[1]);
        z0u.h2[1] = __builtin_amdgcn_cvt_pkrtz(xr0[2], xr0[3]);
        z0u.h2[2] = __builtin_amdgcn_cvt_pkrtz(xr1[0], xr1[1]);
        z0u.h2[3] = __builtin_amdgcn_cvt_pkrtz(xr1[2], xr1[3]);
        z1u.h2[0] = __builtin_amdgcn_cvt_pkrtz(xr2[0], xr2[1]);
        z1u.h2[1] = __builtin_amdgcn_cvt_pkrtz(xr2[2], xr2[3]);
        z1u.h2[2] = __builtin_amdgcn_cvt_pkrtz(xr3[0], xr3[1]);
        z1u.h2[3] = __builtin_amdgcn_cvt_pkrtz(xr3[2], xr3[3]);
        f16x8 z0 = z0u.v, z1 = z1u.v;

        f32x4 acc[4];
        #pragma unroll
        for (int l = 0; l < LAYERS; ++l) {
            // init acc with exact f32 bias from LDS (broadcast within 16-lane group)
            #pragma unroll
            for (int t = 0; t < 4; ++t)
                acc[t] = *(const f32x4*)(smem + BIAS_OFF + l * 256 + t * 64 + g * 16);
            #pragma unroll
            for (int t = 0; t < 4; ++t) {
                f16x8 w0 = *(const f16x8*)(smem + ((size_t)((l * 4 + t) * 2 + 0) * 1024) + lane * 16);
                acc[t] = __builtin_amdgcn_mfma_f32_16x16x32_f16(w0, z0, acc[t], 0, 0, 0);
            }
            #pragma unroll
            for (int t = 0; t < 4; ++t) {
                f16x8 w1 = *(const f16x8*)(smem + ((size_t)((l * 4 + t) * 2 + 1) * 1024) + lane * 16);
                acc[t] = __builtin_amdgcn_mfma_f32_16x16x32_f16(w1, z1, acc[t], 0, 0, 0);
            }

            if (l < LAYERS - 1) {
                // next-layer B fragment = in-lane relu+cast repack of acc:
                // z[kk][j] = relu(acc[2kk + (j>>2)][j&3]) ; packed pairs
                H8 n0, n1;
                #pragma unroll
                for (int t = 0; t < 2; ++t) {
                    n0.h2[t * 2 + 0] = __builtin_amdgcn_cvt_pkrtz(
                        fmaxf(acc[t][0], 0.0f), fmaxf(acc[t][1], 0.0f));
                    n0.h2[t * 2 + 1] = __builtin_amdgcn_cvt_pkrtz(
                        fmaxf(acc[t][2], 0.0f), fmaxf(acc[t][3], 0.0f));
                    n1.h2[t * 2 + 0] = __builtin_amdgcn_cvt_pkrtz(
                        fmaxf(acc[2 + t][0], 0.0f), fmaxf(acc[2 + t][1], 0.0f));
                    n1.h2[t * 2 + 1] = __builtin_amdgcn_cvt_pkrtz(
                        fmaxf(acc[2 + t][2], 0.0f), fmaxf(acc[2 + t][3], 0.0f));
                }
                z0 = n0.v;
                z1 = n1.v;
            }
        }

        // store: f = 16t + 4g + r -> r contiguous -> dwordx4 stores
        float* o = op + (size_t)s * STEP_FLOATS;
        #pragma unroll
        for (int t = 0; t < 4; ++t) {
            f32x4 res;
            #pragma unroll
            for (int r = 0; r < 4; ++r) res[r] = fmaxf(acc[t][r], 0.0f);
            *(f32x4*)(o + t * 16) = res;
        }

        xr0 = xn0; xr1 = xn1; xr2 = xn2; xr3 = xn3;
    }
}

extern "C" void kernel_launch(void* const* d_in, const int* in_sizes, int n_in,
                              void* d_out, int out_size, void* d_ws, size_t ws_size,
                              hipStream_t stream) {
    (void)in_sizes; (void)n_in; (void)out_size; (void)d_ws; (void)ws_size;
    const float* x = (const float*)d_in[0];
    const float* W = (const float*)d_in[1];
    const float* b = (const float*)d_in[2];
    float* out = (float*)d_out;
    mlp4_fused<<<dim3(MODELS * BLOCKS_PER_MODEL), dim3(256), 0, stream>>>(x, W, b, out);
}